// Round 7
// baseline (203.553 us; speedup 1.0000x reference)
//
#include <hip/hip_runtime.h>
#include <hip/hip_bf16.h>

typedef __attribute__((ext_vector_type(8))) short short8;   // 8 bf16 = 4 VGPR (MFMA A/B frag)
typedef __attribute__((ext_vector_type(4))) float f32x4;    // MFMA C/D frag

__device__ __forceinline__ unsigned short f2bf(float f) {
    union { __hip_bfloat16 h; unsigned short u; } cv;
    cv.h = __float2bfloat16(f);   // RNE
    return cv.u;
}

// jax.nn.gelu(approximate=True): 0.5x(1+tanh(sqrt(2/pi)(x+0.044715x^3))) == x*e/(e+1), e=exp(2*inner)
__device__ __forceinline__ float gelu_t(float x) {
    float e = __expf(1.5957691216057308f * x * __builtin_fmaf(0.044715f, x * x, 1.0f));
    return x * (e / (e + 1.0f));
}

__device__ __forceinline__ void gload_lds16(const void* g, void* l) {
    __builtin_amdgcn_global_load_lds((const __attribute__((address_space(1))) unsigned int*)g,
                                     (__attribute__((address_space(3))) unsigned int*)l, 16, 0, 0);
}

// XOR swizzle key for 64B-sliced LDS rows (gemm_small path, verified R3-R6)
__device__ __forceinline__ int swzkey(int r) { return ((r >> 1) & 3) << 4; }

// ---------------------------------------------------------------------------
// Weight prep (one launch).
// z=0/1: We/Wd -> [n][k] bf16, 64B slices XOR swzkey(n)  (gemm_small, verified)
// z=2:   W2 -> FRAGMENT-MAJOR W2f: for frag nf=n>>4, K-step ks=k>>5, lane l:
//        W2f[(nf*16+ks)*1024 + l*16] = W2[ks*32+(l>>4)*8 .. +7][nf*16+(l&15)]
//        -> a wave B-frag load is one fully-contiguous 1KB global_load_dwordx4.
// ---------------------------------------------------------------------------
__global__ __launch_bounds__(256) void transpose_all(const float* __restrict__ W1,
                                                     const float* __restrict__ W2,
                                                     unsigned short* __restrict__ Wet,
                                                     unsigned short* __restrict__ Wdt,
                                                     unsigned short* __restrict__ W2f) {
    int z = blockIdx.z;
    if (z < 2 && blockIdx.y >= 8) return;      // We/Wd have N=512
    const float* in = (z == 0) ? W1 : (z == 1) ? (W1 + 512 * 512) : W2;
    int N = (z == 2) ? 1024 : 512;

    __shared__ float tile[64][65];
    int k0 = blockIdx.x * 64, n0 = blockIdx.y * 64;
    int t = threadIdx.x;
    int c = t & 63, r0 = t >> 6;
#pragma unroll
    for (int i = 0; i < 16; i++) {
        int r = r0 + i * 4;
        tile[r][c] = in[(size_t)(k0 + r) * N + n0 + c];
    }
    __syncthreads();

    if (z < 2) {
        unsigned short* out = (z == 0) ? Wet : Wdt;
        int kk = t & 15;
        int nl0 = t >> 4;
#pragma unroll
        for (int i = 0; i < 4; i++) {
            int nl = nl0 + i * 16;
            int n  = n0 + nl;
            unsigned short b0 = f2bf(tile[kk * 4 + 0][nl]);
            unsigned short b1 = f2bf(tile[kk * 4 + 1][nl]);
            unsigned short b2 = f2bf(tile[kk * 4 + 2][nl]);
            unsigned short b3 = f2bf(tile[kk * 4 + 3][nl]);
            uint2 v;
            v.x = (unsigned)b0 | ((unsigned)b1 << 16);
            v.y = (unsigned)b2 | ((unsigned)b3 << 16);
            int byte_in_chunk = kk * 8;
            int slice = byte_in_chunk & ~63;
            int off   = (byte_in_chunk & 63) ^ swzkey(n);
            size_t obyte = (size_t)n * 1024 + (size_t)k0 * 2 + slice + off;
            *(uint2*)((char*)out + obyte) = v;
        }
    } else {
        // fragment-major pack: 4 nf-frags x 2 K-steps per 64x64 tile
        int lane = t & 63, sub = t >> 6;       // sub = local frag (16 n's)
        int lg = lane >> 4, l15 = lane & 15;
#pragma unroll
        for (int i = 0; i < 2; i++) {
            int ks = blockIdx.x * 2 + i;       // K-step (32 k's)
            unsigned short b[8];
#pragma unroll
            for (int j = 0; j < 8; j++)
                b[j] = f2bf(tile[i * 32 + lg * 8 + j][sub * 16 + l15]);
            uint4 pk;
            pk.x = (unsigned)b[0] | ((unsigned)b[1] << 16);
            pk.y = (unsigned)b[2] | ((unsigned)b[3] << 16);
            pk.z = (unsigned)b[4] | ((unsigned)b[5] << 16);
            pk.w = (unsigned)b[6] | ((unsigned)b[7] << 16);
            size_t obyte = (size_t)(((n0 >> 4) + sub) * 16 + ks) * 1024 + lane * 16;
            *(uint4*)((char*)W2f + obyte) = pk;
        }
    }
}

// ---------------------------------------------------------------------------
// he/hd GEMM (one launch): C[M][512] = A[M][512] @ Bt^T (+bias). (verified R3-R6)
// ---------------------------------------------------------------------------
__global__ __launch_bounds__(256, 2) void gemm_small(const float* __restrict__ enc,
                                                     const float* __restrict__ dec,
                                                     const unsigned short* __restrict__ Wet,
                                                     const unsigned short* __restrict__ Wdt,
                                                     const float* __restrict__ b1,
                                                     float* __restrict__ he,
                                                     float* __restrict__ hd) {
    bool isEnc = blockIdx.x < 8;
    const float* A = isEnc ? enc : dec;
    const unsigned short* Bt = isEnc ? Wet : Wdt;
    const float* bias = isEnc ? b1 : nullptr;
    float* C = isEnc ? he : hd;
    size_t m0 = (size_t)(isEnc ? blockIdx.x : blockIdx.x - 8) * 128;

    __shared__ alignas(16) unsigned short As[128 * 32];
    __shared__ alignas(16) unsigned short Bs[128 * 32];
    int t = threadIdx.x;
    int n0 = blockIdx.y * 128;
    int lane = t & 63, w = t >> 6;
    int wm = w >> 1, wn = w & 1;
    int rA = t >> 3, cg = t & 7;
    f32x4 acc[4][4] = {};

    for (int kt = 0; kt < 16; ++kt) {
        int k0 = kt * 32;
        __syncthreads();
#pragma unroll
        for (int p = 0; p < 4; p++) {
            int r = rA + p * 32;
            f32x4 v = *(const f32x4*)&A[(m0 + r) * 512 + k0 + cg * 4];
            uint2 pk;
            pk.x = (unsigned)f2bf(v.x) | ((unsigned)f2bf(v.y) << 16);
            pk.y = (unsigned)f2bf(v.z) | ((unsigned)f2bf(v.w) << 16);
            int off = (cg * 8) ^ swzkey(r);
            *(uint2*)((char*)As + r * 64 + off) = pk;
        }
#pragma unroll
        for (int j = 0; j < 2; j++) {
            int ibyte = w * 1024 + j * 4096;
            int lb = ibyte + lane * 16;
            int row = lb >> 6, colb = lb & 63;
            const char* src = (const char*)Bt + (size_t)(n0 + row) * 1024 + k0 * 2 + colb;
            gload_lds16(src, (char*)Bs + ibyte);
        }
        __syncthreads();
        short8 af[4], bf[4];
#pragma unroll
        for (int mi = 0; mi < 4; mi++) {
            int r = wm * 64 + mi * 16 + (lane & 15);
            int off = ((lane >> 4) * 16) ^ swzkey(r);
            af[mi] = *(const short8*)((const char*)As + r * 64 + off);
        }
#pragma unroll
        for (int ni = 0; ni < 4; ni++) {
            int n = wn * 64 + ni * 16 + (lane & 15);
            int off = ((lane >> 4) * 16) ^ swzkey(n);
            bf[ni] = *(const short8*)((const char*)Bs + n * 64 + off);
        }
#pragma unroll
        for (int mi = 0; mi < 4; mi++)
#pragma unroll
            for (int ni = 0; ni < 4; ni++)
                acc[mi][ni] = __builtin_amdgcn_mfma_f32_16x16x32_bf16(af[mi], bf[ni], acc[mi][ni], 0, 0, 0);
    }
#pragma unroll
    for (int mi = 0; mi < 4; mi++) {
        int row = wm * 64 + mi * 16 + ((lane >> 4) << 2);
#pragma unroll
        for (int ni = 0; ni < 4; ni++) {
            int col = n0 + wn * 64 + ni * 16 + (lane & 15);
            float bv = bias ? bias[col] : 0.0f;
#pragma unroll
            for (int q = 0; q < 4; q++)
                C[(m0 + row + q) * 512 + col] = acc[mi][ni][q] + bv;
        }
    }
}

// ---------------------------------------------------------------------------
// Fused joint, BARRIER-FREE K-loop:
//   prologue: gelu(he+hd) -> h[64][512] bf16 in LDS (XOR-swizzled), 1 barrier.
//   K-loop:   A-frags from read-only LDS, B-frags streamed L2->reg from
//             fragment-major W2f (1KB contiguous per wave-load, depth-1
//             prefetch), 16 MFMA/step under setprio. NO barriers.
//   epilogue: 1 barrier, LDS pad reuse, 16B/lane contiguous NT stores.
// BM=64 BN=512, 512 thr, 8 waves 1m x 8n (wave = 64 rows x 64 cols, acc[4][4]).
// LDS 64KB -> 2 blocks/CU; VGPR target <=128.
// ---------------------------------------------------------------------------
__global__ __launch_bounds__(512, 4) void joint_fused(const float* __restrict__ he,
                                                      const float* __restrict__ hd,
                                                      const unsigned short* __restrict__ W2f,
                                                      float* __restrict__ out) {
    __shared__ alignas(16) char lds[65536];    // h-tile; epilogue pad reuses it
    int t = threadIdx.x;
    int lane = t & 63, w = t >> 6;
    int bx = blockIdx.x;                       // 0..1535, XCD swizzle (1536%8==0 bijective)
    int mt = (bx & 7) * 192 + (bx >> 3);
    size_t m0 = (size_t)mt * 64;
    int n0 = blockIdx.y * 512;

    // ---- prologue: generate h[64][512] bf16, swizzled: byte = r*1024 + (k*2 ^ ((r&7)<<4))
    {
        int r = t >> 3, kc = t & 7;            // 8 threads per row, 8 k's per group
        int mrow = (int)m0 + r;
        int tI = mrow / 96;
        int u  = mrow - tI * 96;
        const float* eP = he + (size_t)tI * 512;
        const float* dP = hd + (size_t)((tI >> 8) * 96 + u) * 512;
        unsigned key = (unsigned)((r & 7) << 4);
        char* hb = lds + r * 1024;
#pragma unroll
        for (int g = 0; g < 8; g++) {
            int k = g * 64 + kc * 8;           // lanes kc=0..7 contiguous within 128B
            f32x4 e0 = *(const f32x4*)(eP + k);
            f32x4 d0 = *(const f32x4*)(dP + k);
            f32x4 e1 = *(const f32x4*)(eP + k + 4);
            f32x4 d1 = *(const f32x4*)(dP + k + 4);
            uint4 pk;
            pk.x = (unsigned)f2bf(gelu_t(e0.x + d0.x)) | ((unsigned)f2bf(gelu_t(e0.y + d0.y)) << 16);
            pk.y = (unsigned)f2bf(gelu_t(e0.z + d0.z)) | ((unsigned)f2bf(gelu_t(e0.w + d0.w)) << 16);
            pk.z = (unsigned)f2bf(gelu_t(e1.x + d1.x)) | ((unsigned)f2bf(gelu_t(e1.y + d1.y)) << 16);
            pk.w = (unsigned)f2bf(gelu_t(e1.z + d1.z)) | ((unsigned)f2bf(gelu_t(e1.w + d1.w)) << 16);
            *(uint4*)(hb + ((unsigned)(k * 2) ^ key)) = pk;
        }
    }
    __syncthreads();

    // ---- K-loop setup
    int l15 = lane & 15, lg = lane >> 4;
    unsigned akey = (unsigned)((l15 & 7) << 4);
    const char* aB = lds + l15 * 1024;         // + mi*16384 + (ks>>1)*128 + aoff[ks&1]
    int aoff[2] = { (int)((unsigned)(lg * 16) ^ akey),
                    (int)((unsigned)(64 + lg * 16) ^ akey) };
    // B pointers: wave w covers frags nf = n0/16 + w*4 + ni
    const char* bP[4];
#pragma unroll
    for (int ni = 0; ni < 4; ni++)
        bP[ni] = (const char*)W2f + (size_t)(((n0 >> 4) + w * 4 + ni) * 16) * 1024 + lane * 16;

    f32x4 acc[4][4] = {};
    short8 bA[4], bB[4];
#pragma unroll
    for (int ni = 0; ni < 4; ni++) bA[ni] = *(const short8*)(bP[ni]);

#define STEP(BC, BN_, ks) do {                                                              \
        if ((ks) < 15) {                                                                    \
            _Pragma("unroll")                                                               \
            for (int ni = 0; ni < 4; ni++)                                                  \
                BN_[ni] = *(const short8*)(bP[ni] + ((ks) + 1) * 1024);                     \
        }                                                                                   \
        short8 a[4];                                                                        \
        _Pragma("unroll")                                                                   \
        for (int mi = 0; mi < 4; mi++)                                                      \
            a[mi] = *(const short8*)(aB + mi * 16384 + ((ks) >> 1) * 128 + aoff[(ks) & 1]); \
        __builtin_amdgcn_s_setprio(1);                                                      \
        _Pragma("unroll")                                                                   \
        for (int ni = 0; ni < 4; ni++)                                                      \
            _Pragma("unroll")                                                               \
            for (int mi = 0; mi < 4; mi++)                                                  \
                acc[mi][ni] = __builtin_amdgcn_mfma_f32_16x16x32_bf16(a[mi], BC[ni],        \
                                                                     acc[mi][ni], 0, 0, 0); \
        __builtin_amdgcn_s_setprio(0);                                                      \
    } while (0)

#pragma unroll
    for (int kp = 0; kp < 8; kp++) {
        STEP(bA, bB, kp * 2);
        STEP(bB, bA, kp * 2 + 1);
    }
#undef STEP

    __syncthreads();                            // h dead -> LDS reusable as epilogue pad

    // ---- epilogue: per-wave pad 16 rows x 76 f32 (304 B stride), then NT 16B/lane
    char* ep = lds + w * 4864;
#pragma unroll
    for (int mi = 0; mi < 4; mi++) {
        // scatter acc into row-major pad (C/D layout: col=l15, row=lg*4+q)
#pragma unroll
        for (int ni = 0; ni < 4; ni++)
#pragma unroll
            for (int q = 0; q < 4; q++)
                *(float*)(ep + (lg * 4 + q) * 304 + (ni * 16 + l15) * 4) = acc[mi][ni][q];
        asm volatile("s_waitcnt lgkmcnt(0)" ::: "memory");
        __builtin_amdgcn_sched_barrier(0);
        // read back contiguous rows, 16B/lane -> 256B contiguous per 16-lane group
#pragma unroll
        for (int it = 0; it < 4; it++) {
            int r = it * 4 + lg;
            f32x4 v = *(const f32x4*)(ep + r * 304 + l15 * 16);
            size_t row = m0 + mi * 16 + r;
            float* o = out + row * 1024 + n0 + w * 64 + l15 * 4;
            __builtin_nontemporal_store(v, (f32x4*)o);
        }
        asm volatile("s_waitcnt lgkmcnt(0)" ::: "memory");   // reads done before next mi
        __builtin_amdgcn_sched_barrier(0);
    }
}

extern "C" void kernel_launch(void* const* d_in, const int* in_sizes, int n_in,
                              void* d_out, int out_size, void* d_ws, size_t ws_size,
                              hipStream_t stream) {
    const float* enc = (const float*)d_in[0];   // (4,256,512)
    const float* dec = (const float*)d_in[1];   // (4,96,512)
    const float* W1  = (const float*)d_in[2];   // (1024,512)
    const float* b1  = (const float*)d_in[3];   // (512,)
    const float* W2  = (const float*)d_in[4];   // (512,1024)
    float* out = (float*)d_out;                 // (4,256,96,1024) f32

    char* ws = (char*)d_ws;
    float* he = (float*)(ws);                               // 1024x512 f32 (b1 folded)
    float* hd = (float*)(ws + 2097152);                     //  384x512 f32
    unsigned short* Wet = (unsigned short*)(ws + 2883584);  // 512x512 bf16 swz
    unsigned short* Wdt = (unsigned short*)(ws + 3407872);  // 512x512 bf16 swz
    unsigned short* W2f = (unsigned short*)(ws + 3932160);  // 1024x512 bf16 frag-major

    transpose_all<<<dim3(8, 16, 3), 256, 0, stream>>>(W1, W2, Wet, Wdt, W2f);
    gemm_small<<<dim3(11, 4), 256, 0, stream>>>(enc, dec, Wet, Wdt, b1, he, hd);
    joint_fused<<<dim3(1536, 2), 512, 0, stream>>>(he, hd, W2f, out);
}